// Round 1
// baseline (191.930 us; speedup 1.0000x reference)
//
#include <hip/hip_runtime.h>
#include <hip/hip_bf16.h>
#include <stdint.h>

// GRU cell, B=32768, IN=256, H=256, CONCAT=512.
// Fused single-pass kernel: bf16 MFMA (16x16x32), weights pre-swizzled into
// MFMA B-fragment order in d_ws by a small prep kernel.

typedef float  f32x4  __attribute__((ext_vector_type(4)));
typedef __bf16 bf16x8 __attribute__((ext_vector_type(8)));
typedef short  s16x8  __attribute__((ext_vector_type(8)));

#define B_TOT   32768
#define HDIM    256
#define KCAT    512
#define MT      64            // rows per block
#define WRZ_ELEMS (512*512)   // combined r|z weights, bf16
#define WG_ELEMS  (256*512)   // combined [whx;whh] weights, bf16

__device__ __forceinline__ unsigned short f2b(float f) {
    union { float f; unsigned int u; } v; v.f = f;
    unsigned int r = (v.u + 0x7FFFu + ((v.u >> 16) & 1u)) >> 16;  // RNE
    return (unsigned short)r;
}
__device__ __forceinline__ float b2f(unsigned short b) {
    union { unsigned int u; float f; } v; v.u = ((unsigned int)b) << 16;
    return v.f;
}
__device__ __forceinline__ float sigmoid_f(float x) {
    return 1.0f / (1.0f + __expf(-x));
}
__device__ __forceinline__ float tanh_f(float x) {
    return 1.0f - 2.0f / (__expf(2.0f * x) + 1.0f);
}

// LDS tile: 64 rows x 512 cols bf16 = 64 KB, XOR-swizzled at 16B granularity
// (8 bf16 elems) so that strided row accesses (stride 1024 B) don't all land
// on bank 0. Element (row,col) -> row*512 + ((col>>3 ^ (row&7))<<3 | col&7).
__device__ __forceinline__ int lds_idx(int row, int col) {
    return row * 512 + ((((col >> 3) ^ (row & 7)) << 3) | (col & 7));
}

// ---------------------------------------------------------------------------
// Prep kernel: convert fp32 weights to bf16 and lay them out in exact MFMA
// B-fragment order: block (nt,ks) is 1 KB; within it lane l holds
// B[k = ks*32 + (l>>4)*8 + j][n = nt*16 + (l&15)], j=0..7 contiguous.
// wrz column space (512) is permuted so wave w (=c>>7) owns r-cols
// [64w,64w+64) at t<64 and z-cols [64w,64w+64) at t>=64 (t = c&127).
// wg k-space: k<256 -> whx (x part), k>=256 -> whh (a part).
// ---------------------------------------------------------------------------
__global__ void swizzle_weights(const float* __restrict__ wr,
                                const float* __restrict__ wz,
                                const float* __restrict__ whh,
                                const float* __restrict__ whx,
                                unsigned short* __restrict__ wrz,
                                unsigned short* __restrict__ wg) {
    int i = blockIdx.x * blockDim.x + threadIdx.x;
    if (i < WRZ_ELEMS) {
        int blk  = i >> 9;          // nt*16 + ks
        int lane = (i >> 3) & 63;
        int j    = i & 7;
        int nt = blk >> 4, ks = blk & 15;
        int c  = nt * 16 + (lane & 15);                // combined col 0..511
        int k  = ks * 32 + ((lane >> 4) << 3) + j;     // 0..511
        int w  = c >> 7, t = c & 127;
        float v = (t < 64) ? wr[k * 256 + (w * 64 + t)]
                           : wz[k * 256 + (w * 64 + t - 64)];
        wrz[i] = f2b(v);
    } else {
        int i2 = i - WRZ_ELEMS;
        if (i2 < WG_ELEMS) {
            int blk  = i2 >> 9;
            int lane = (i2 >> 3) & 63;
            int j    = i2 & 7;
            int nt = blk >> 4, ks = blk & 15;
            int n  = nt * 16 + (lane & 15);            // 0..255
            int k  = ks * 32 + ((lane >> 4) << 3) + j; // 0..511
            float v = (k < 256) ? whx[k * 256 + n] : whh[(k - 256) * 256 + n];
            wg[i2] = f2b(v);
        }
    }
}

// ---------------------------------------------------------------------------
// Fused GRU kernel. One block = 64 rows, 4 waves. Wave w owns output columns
// [64w, 64w+64). LDS tile holds [x | h] bf16, later h-region is overwritten
// with a = sigmoid(r)*h for GEMM2 ([x | a] @ [whx; whh]).
// ---------------------------------------------------------------------------
__global__ __launch_bounds__(256, 2)
void gru_fused(const float* __restrict__ x, const float* __restrict__ h,
               const unsigned short* __restrict__ wrz,
               const unsigned short* __restrict__ wg,
               const float* __restrict__ br, const float* __restrict__ bz,
               const float* __restrict__ bh, float* __restrict__ out) {
    __shared__ unsigned short xcA[64 * 512];   // 64 KB

    const int tid  = threadIdx.x;
    const int lane = tid & 63;
    const int wv   = tid >> 6;          // wave 0..3
    const int m0   = lane & 15;
    const int q    = lane >> 4;         // quad 0..3
    const int rowBase = blockIdx.x * MT;

    // ---- Stage [x | h] -> LDS bf16. Each wave: rows it*4+wv, lane covers
    // 4 consecutive cols (16 B global float4 -> 8 B LDS ushort4).
    for (int it = 0; it < 16; ++it) {
        int row = it * 4 + wv;
        size_t g = (size_t)(rowBase + row) * 256 + lane * 4;
        float4 xv = *reinterpret_cast<const float4*>(x + g);
        float4 hv = *reinterpret_cast<const float4*>(h + g);
        ushort4 xb, hb;
        xb.x = f2b(xv.x); xb.y = f2b(xv.y); xb.z = f2b(xv.z); xb.w = f2b(xv.w);
        hb.x = f2b(hv.x); hb.y = f2b(hv.y); hb.z = f2b(hv.z); hb.w = f2b(hv.w);
        *reinterpret_cast<ushort4*>(&xcA[lds_idx(row, lane * 4)])       = xb;
        *reinterpret_cast<ushort4*>(&xcA[lds_idx(row, 256 + lane * 4)]) = hb;
    }
    __syncthreads();

    // ---- GEMM1: [64,512] @ [512,512] -> r|z logits (wave-interleaved cols)
    f32x4 acc[8][4];
    #pragma unroll
    for (int jn = 0; jn < 8; ++jn)
        #pragma unroll
        for (int mt = 0; mt < 4; ++mt)
            acc[jn][mt] = (f32x4){0.f, 0.f, 0.f, 0.f};

    const unsigned short* wrzW = wrz + (size_t)(8 * wv) * 16 * 512;
    for (int ks = 0; ks < 16; ++ks) {
        bf16x8 afr[4];
        #pragma unroll
        for (int mt = 0; mt < 4; ++mt) {
            s16x8 raw = *reinterpret_cast<const s16x8*>(
                &xcA[lds_idx(mt * 16 + m0, ks * 32 + q * 8)]);
            afr[mt] = __builtin_bit_cast(bf16x8, raw);
        }
        #pragma unroll
        for (int jn = 0; jn < 8; ++jn) {
            s16x8 braw = *reinterpret_cast<const s16x8*>(
                wrzW + (size_t)(jn * 16 + ks) * 512 + lane * 8);
            bf16x8 bfr = __builtin_bit_cast(bf16x8, braw);
            #pragma unroll
            for (int mt = 0; mt < 4; ++mt)
                acc[jn][mt] = __builtin_amdgcn_mfma_f32_16x16x32_bf16(
                    afr[mt], bfr, acc[jn][mt], 0, 0, 0);
        }
    }
    __syncthreads();   // all GEMM1 LDS reads done before h-region overwrite

    // ---- Gates: a = sigmoid(r+br)*h -> LDS (over h region);
    //      acc[j] <- (1-z)*h (blend term), acc[4+j] <- z.
    #pragma unroll
    for (int j = 0; j < 4; ++j) {
        int col = 64 * wv + j * 16 + m0;       // H column, C-layout
        float brv = br[col];
        float bzv = bz[col];
        #pragma unroll
        for (int mt = 0; mt < 4; ++mt) {
            #pragma unroll
            for (int rg = 0; rg < 4; ++rg) {
                int row = mt * 16 + q * 4 + rg;
                int hid = lds_idx(row, 256 + col);
                float hval = b2f(xcA[hid]);
                float rs = sigmoid_f(acc[j][mt][rg] + brv);
                float zs = sigmoid_f(acc[4 + j][mt][rg] + bzv);
                xcA[hid] = f2b(rs * hval);             // a = r*h (wave-private)
                acc[j][mt][rg]     = (1.0f - zs) * hval;
                acc[4 + j][mt][rg] = zs;
            }
        }
    }
    __syncthreads();   // a visible to all waves

    // ---- GEMM2: [x | a] @ [whx; whh] -> g logits
    f32x4 gacc[4][4];
    #pragma unroll
    for (int j = 0; j < 4; ++j)
        #pragma unroll
        for (int mt = 0; mt < 4; ++mt)
            gacc[j][mt] = (f32x4){0.f, 0.f, 0.f, 0.f};

    const unsigned short* wgW = wg + (size_t)(4 * wv) * 16 * 512;
    for (int ks = 0; ks < 16; ++ks) {
        bf16x8 afr[4];
        #pragma unroll
        for (int mt = 0; mt < 4; ++mt) {
            s16x8 raw = *reinterpret_cast<const s16x8*>(
                &xcA[lds_idx(mt * 16 + m0, ks * 32 + q * 8)]);
            afr[mt] = __builtin_bit_cast(bf16x8, raw);
        }
        #pragma unroll
        for (int j = 0; j < 4; ++j) {
            s16x8 braw = *reinterpret_cast<const s16x8*>(
                wgW + (size_t)(j * 16 + ks) * 512 + lane * 8);
            bf16x8 bfr = __builtin_bit_cast(bf16x8, braw);
            #pragma unroll
            for (int mt = 0; mt < 4; ++mt)
                gacc[j][mt] = __builtin_amdgcn_mfma_f32_16x16x32_bf16(
                    afr[mt], bfr, gacc[j][mt], 0, 0, 0);
        }
    }

    // ---- Epilogue: h_out = (1-z)*h + z*tanh(g + bh)
    #pragma unroll
    for (int j = 0; j < 4; ++j) {
        int col = 64 * wv + j * 16 + m0;
        float bhv = bh[col];
        #pragma unroll
        for (int mt = 0; mt < 4; ++mt) {
            #pragma unroll
            for (int rg = 0; rg < 4; ++rg) {
                int row = mt * 16 + q * 4 + rg;
                float g = tanh_f(gacc[j][mt][rg] + bhv);
                float o = acc[j][mt][rg] + acc[4 + j][mt][rg] * g;
                out[(size_t)(rowBase + row) * 256 + col] = o;
            }
        }
    }
}

extern "C" void kernel_launch(void* const* d_in, const int* in_sizes, int n_in,
                              void* d_out, int out_size, void* d_ws, size_t ws_size,
                              hipStream_t stream) {
    const float* x   = (const float*)d_in[0];
    const float* h   = (const float*)d_in[1];
    const float* wr  = (const float*)d_in[2];
    const float* wz  = (const float*)d_in[3];
    const float* whh = (const float*)d_in[4];
    const float* whx = (const float*)d_in[5];
    const float* br  = (const float*)d_in[6];
    const float* bz  = (const float*)d_in[7];
    const float* bh  = (const float*)d_in[8];
    float* out = (float*)d_out;

    unsigned short* wrz = (unsigned short*)d_ws;       // 512 KB
    unsigned short* wg  = wrz + WRZ_ELEMS;             // 256 KB

    const int totalW = WRZ_ELEMS + WG_ELEMS;           // 393216
    swizzle_weights<<<totalW / 256, 256, 0, stream>>>(wr, wz, whh, whx, wrz, wg);
    gru_fused<<<B_TOT / MT, 256, 0, stream>>>(x, h, wrz, wg, br, bz, bh, out);
}

// Round 2
// 185.035 us; speedup vs baseline: 1.0373x; 1.0373x over previous
//
#include <hip/hip_runtime.h>
#include <hip/hip_bf16.h>
#include <stdint.h>

// GRU cell, B=32768, IN=256, H=256, CONCAT=512. Fused bf16-MFMA kernel.
// R2: 512-thread blocks (16 waves/CU vs 8), bf16-packed blend/z to fit
// VGPR<=128, LDS-transposed coalesced epilogue, coalesced-read prep kernel.

typedef float  f32x4  __attribute__((ext_vector_type(4)));
typedef __bf16 bf16x8 __attribute__((ext_vector_type(8)));
typedef short  s16x8  __attribute__((ext_vector_type(8)));

#define B_TOT   32768
#define MT      64            // rows per block
#define WRZ_ELEMS (512*512)   // combined r|z weights, bf16
#define WG_ELEMS  (256*512)   // combined [whx;whh] weights, bf16

__device__ __forceinline__ unsigned short f2b(float f) {
    union { float f; unsigned int u; } v; v.f = f;
    unsigned int r = (v.u + 0x7FFFu + ((v.u >> 16) & 1u)) >> 16;  // RNE
    return (unsigned short)r;
}
__device__ __forceinline__ float b2f(unsigned short b) {
    union { unsigned int u; float f; } v; v.u = ((unsigned int)b) << 16;
    return v.f;
}
__device__ __forceinline__ float sigmoid_f(float x) {
    return 1.0f / (1.0f + __expf(-x));
}
__device__ __forceinline__ float tanh_f(float x) {
    return 1.0f - 2.0f / (__expf(2.0f * x) + 1.0f);
}

// bf16 LDS tile 64x512 (64 KB), XOR-swizzled at 16B (8-elem) granularity.
__device__ __forceinline__ int lds_idx(int row, int col) {
    return row * 512 + ((((col >> 3) ^ (row & 7)) << 3) | (col & 7));
}
// fp32 output-staging view of the same LDS, XOR-swizzled at 16B (4-float).
__device__ __forceinline__ int fidx(int row, int col) {
    return row * 256 + ((((col >> 2) ^ (row & 63)) << 2) | (col & 3));
}

// ---------------------------------------------------------------------------
// Prep: fp32 -> bf16, laid out in MFMA B-fragment order. Coalesced READS
// (one thread per source element), scattered 2B writes (fire-and-forget).
// B-frag block (nt,ks) is 1 KB: lane l holds B[k=ks*32+(l>>4)*8+j][n=nt*16+(l&15)].
// wrz col space permuted: wave w (c>>6) owns r-cols [32w,32w+32) at t<32 and
// z-cols [32w,32w+32) at t>=32 (t=c&63).
// wg k-space: k<256 -> whx, k>=256 -> whh.
// ---------------------------------------------------------------------------
__global__ void swizzle_weights(const float* __restrict__ wr,
                                const float* __restrict__ wz,
                                const float* __restrict__ whh,
                                const float* __restrict__ whx,
                                unsigned short* __restrict__ wrz,
                                unsigned short* __restrict__ wg) {
    int i = blockIdx.x * blockDim.x + threadIdx.x;
    if (i < 131072) {                      // wr
        int k = i >> 8, n = i & 255;
        int c = ((n >> 5) << 6) + (n & 31);
        int nt = c >> 4, ct = c & 15;
        int ks = k >> 5, kq = (k >> 3) & 3, jj = k & 7;
        wrz[(((nt << 4) + ks) << 9) + (kq * 16 + ct) * 8 + jj] = f2b(wr[i]);
    } else if (i < 262144) {               // wz
        int i2 = i - 131072;
        int k = i2 >> 8, n = i2 & 255;
        int c = ((n >> 5) << 6) + 32 + (n & 31);
        int nt = c >> 4, ct = c & 15;
        int ks = k >> 5, kq = (k >> 3) & 3, jj = k & 7;
        wrz[(((nt << 4) + ks) << 9) + (kq * 16 + ct) * 8 + jj] = f2b(wz[i2]);
    } else if (i < 327680) {               // whx (k 0..255)
        int i2 = i - 262144;
        int k = i2 >> 8, n = i2 & 255;
        int nt = n >> 4, ct = n & 15;
        int ks = k >> 5, kq = (k >> 3) & 3, jj = k & 7;
        wg[(((nt << 4) + ks) << 9) + (kq * 16 + ct) * 8 + jj] = f2b(whx[i2]);
    } else {                               // whh (k 256..511)
        int i2 = i - 327680;
        int kk = i2 >> 8, n = i2 & 255;
        int k = 256 + kk;
        int nt = n >> 4, ct = n & 15;
        int ks = k >> 5, kq = (k >> 3) & 3, jj = k & 7;
        wg[(((nt << 4) + ks) << 9) + (kq * 16 + ct) * 8 + jj] = f2b(whh[i2]);
    }
}

// ---------------------------------------------------------------------------
// Fused GRU kernel: 512 threads (8 waves), 64 rows/block. Wave w owns output
// cols [32w, 32w+32). LDS holds [x|h] bf16; h-region overwritten with
// a = sigmoid(r)*h for GEMM2; finally LDS reused as fp32 out-staging.
// ---------------------------------------------------------------------------
__global__ __launch_bounds__(512, 4)
void gru_fused(const float* __restrict__ x, const float* __restrict__ h,
               const unsigned short* __restrict__ wrz,
               const unsigned short* __restrict__ wg,
               const float* __restrict__ br, const float* __restrict__ bz,
               const float* __restrict__ bh, float* __restrict__ out) {
    __shared__ unsigned short xcA[64 * 512];   // 64 KB

    const int tid  = threadIdx.x;
    const int lane = tid & 63;
    const int wv   = tid >> 6;          // wave 0..7
    const int m0   = lane & 15;
    const int q    = lane >> 4;         // quad 0..3
    const int rowBase = blockIdx.x * MT;

    // ---- Stage [x | h] -> LDS bf16 (8 iters, 8 rows per wave)
    #pragma unroll
    for (int it = 0; it < 8; ++it) {
        int row = it * 8 + wv;
        size_t g = (size_t)(rowBase + row) * 256 + lane * 4;
        float4 xv = *reinterpret_cast<const float4*>(x + g);
        float4 hv = *reinterpret_cast<const float4*>(h + g);
        ushort4 xb, hb;
        xb.x = f2b(xv.x); xb.y = f2b(xv.y); xb.z = f2b(xv.z); xb.w = f2b(xv.w);
        hb.x = f2b(hv.x); hb.y = f2b(hv.y); hb.z = f2b(hv.z); hb.w = f2b(hv.w);
        *reinterpret_cast<ushort4*>(&xcA[lds_idx(row, lane * 4)])       = xb;
        *reinterpret_cast<ushort4*>(&xcA[lds_idx(row, 256 + lane * 4)]) = hb;
    }
    __syncthreads();

    // ---- GEMM1: [64,512] @ [512, 64-per-wave] -> r|z logits
    f32x4 acc[4][4];
    #pragma unroll
    for (int jn = 0; jn < 4; ++jn)
        #pragma unroll
        for (int mt = 0; mt < 4; ++mt)
            acc[jn][mt] = (f32x4){0.f, 0.f, 0.f, 0.f};

    const unsigned short* wrzW = wrz + (size_t)(4 * wv) * 16 * 512;
    for (int ks = 0; ks < 16; ++ks) {
        bf16x8 afr[4];
        #pragma unroll
        for (int mt = 0; mt < 4; ++mt) {
            s16x8 raw = *reinterpret_cast<const s16x8*>(
                &xcA[lds_idx(mt * 16 + m0, ks * 32 + q * 8)]);
            afr[mt] = __builtin_bit_cast(bf16x8, raw);
        }
        #pragma unroll
        for (int jn = 0; jn < 4; ++jn) {
            s16x8 braw = *reinterpret_cast<const s16x8*>(
                wrzW + (((jn << 4) + ks) << 9) + lane * 8);
            bf16x8 bfr = __builtin_bit_cast(bf16x8, braw);
            #pragma unroll
            for (int mt = 0; mt < 4; ++mt)
                acc[jn][mt] = __builtin_amdgcn_mfma_f32_16x16x32_bf16(
                    afr[mt], bfr, acc[jn][mt], 0, 0, 0);
        }
    }
    __syncthreads();   // GEMM1 LDS reads done before h-region overwrite

    // ---- Gates: a = sigmoid(r+br)*h -> LDS (h region);
    //      pk = packed bf16 {blend=(1-z)*h, z}
    unsigned int pk[2][4][4];
    #pragma unroll
    for (int j = 0; j < 2; ++j) {
        int col = 32 * wv + j * 16 + m0;
        float brv = br[col];
        float bzv = bz[col];
        #pragma unroll
        for (int mt = 0; mt < 4; ++mt) {
            #pragma unroll
            for (int rg = 0; rg < 4; ++rg) {
                int row = mt * 16 + q * 4 + rg;
                int hid = lds_idx(row, 256 + col);
                float hval = b2f(xcA[hid]);
                float rs = sigmoid_f(acc[j][mt][rg] + brv);
                float zs = sigmoid_f(acc[2 + j][mt][rg] + bzv);
                xcA[hid] = f2b(rs * hval);             // a = r*h
                float blend = (1.0f - zs) * hval;
                pk[j][mt][rg] = (unsigned int)f2b(blend)
                              | ((unsigned int)f2b(zs) << 16);
            }
        }
    }
    __syncthreads();   // a visible to all waves

    // ---- GEMM2: [x | a] @ [whx; whh] -> g logits
    f32x4 gacc[2][4];
    #pragma unroll
    for (int j = 0; j < 2; ++j)
        #pragma unroll
        for (int mt = 0; mt < 4; ++mt)
            gacc[j][mt] = (f32x4){0.f, 0.f, 0.f, 0.f};

    const unsigned short* wgW = wg + (size_t)(2 * wv) * 16 * 512;
    for (int ks = 0; ks < 16; ++ks) {
        bf16x8 afr[4];
        #pragma unroll
        for (int mt = 0; mt < 4; ++mt) {
            s16x8 raw = *reinterpret_cast<const s16x8*>(
                &xcA[lds_idx(mt * 16 + m0, ks * 32 + q * 8)]);
            afr[mt] = __builtin_bit_cast(bf16x8, raw);
        }
        #pragma unroll
        for (int j = 0; j < 2; ++j) {
            s16x8 braw = *reinterpret_cast<const s16x8*>(
                wgW + (((j << 4) + ks) << 9) + lane * 8);
            bf16x8 bfr = __builtin_bit_cast(bf16x8, braw);
            #pragma unroll
            for (int mt = 0; mt < 4; ++mt)
                gacc[j][mt] = __builtin_amdgcn_mfma_f32_16x16x32_bf16(
                    afr[mt], bfr, gacc[j][mt], 0, 0, 0);
        }
    }
    __syncthreads();   // all LDS A-reads done; reuse LDS as fp32 staging

    // ---- Epilogue: h_out = blend + z*tanh(g+bh) -> LDS fp32 (swizzled)
    float* ofl = reinterpret_cast<float*>(xcA);
    #pragma unroll
    for (int j = 0; j < 2; ++j) {
        int col = 32 * wv + j * 16 + m0;
        float bhv = bh[col];
        #pragma unroll
        for (int mt = 0; mt < 4; ++mt) {
            #pragma unroll
            for (int rg = 0; rg < 4; ++rg) {
                int row = mt * 16 + q * 4 + rg;
                float g = tanh_f(gacc[j][mt][rg] + bhv);
                unsigned int p = pk[j][mt][rg];
                float blend = b2f((unsigned short)(p & 0xFFFF));
                float zs    = b2f((unsigned short)(p >> 16));
                ofl[fidx(row, col)] = blend + zs * g;
            }
        }
    }
    __syncthreads();

    // ---- Coalesced store: each wave stores 8 full rows (1 KB each)
    #pragma unroll
    for (int it = 0; it < 8; ++it) {
        int R = wv * 8 + it;
        float4 v = *reinterpret_cast<const float4*>(&ofl[fidx(R, lane * 4)]);
        *reinterpret_cast<float4*>(out + (size_t)(rowBase + R) * 256 + lane * 4) = v;
    }
}

extern "C" void kernel_launch(void* const* d_in, const int* in_sizes, int n_in,
                              void* d_out, int out_size, void* d_ws, size_t ws_size,
                              hipStream_t stream) {
    const float* x   = (const float*)d_in[0];
    const float* h   = (const float*)d_in[1];
    const float* wr  = (const float*)d_in[2];
    const float* wz  = (const float*)d_in[3];
    const float* whh = (const float*)d_in[4];
    const float* whx = (const float*)d_in[5];
    const float* br  = (const float*)d_in[6];
    const float* bz  = (const float*)d_in[7];
    const float* bh  = (const float*)d_in[8];
    float* out = (float*)d_out;

    unsigned short* wrz = (unsigned short*)d_ws;       // 512 KB
    unsigned short* wg  = wrz + WRZ_ELEMS;             // 256 KB

    const int totalW = WRZ_ELEMS + WG_ELEMS;           // 393216
    swizzle_weights<<<totalW / 256, 256, 0, stream>>>(wr, wz, whh, whx, wrz, wg);
    gru_fused<<<B_TOT / MT, 512, 0, stream>>>(x, h, wrz, wg, br, bz, bh, out);
}